// Round 2
// baseline (1055.991 us; speedup 1.0000x reference)
//
#include <hip/hip_runtime.h>

#define BLK 256

// ======================= common small kernels =======================

// degree histogram (int): hist[dst[e]] += 1
__global__ __launch_bounds__(BLK) void k_hist(const int* __restrict__ dst, int E, int N,
                                              int* __restrict__ hist) {
    int i = blockIdx.x * BLK + threadIdx.x;
    if (i < E) {
        int d = dst[i];
        if ((unsigned)d < (unsigned)N) atomicAdd(&hist[d], 1);
    }
}

// dinv[i] = rsqrt(deg_edges + 1 self-loop)
__global__ __launch_bounds__(BLK) void k_dinv_i(const int* __restrict__ hist,
                                                float* __restrict__ dinv, int N) {
    int i = blockIdx.x * BLK + threadIdx.x;
    if (i < N) dinv[i] = rsqrtf((float)hist[i] + 1.0f);
}

// g1[i][j] = (x[i] @ W1)[j] * dinv[i]   (32 -> 16)
__global__ __launch_bounds__(BLK) void k_transform1(const float* __restrict__ x,
                                                    const float* __restrict__ W1,
                                                    const float* __restrict__ dinv,
                                                    float* __restrict__ g1, int N) {
    __shared__ float sW[32 * 16];
    for (int t = threadIdx.x; t < 512; t += BLK) sW[t] = W1[t];
    __syncthreads();
    int i = blockIdx.x * BLK + threadIdx.x;
    if (i >= N) return;
    float xr[32];
    const float4* xp = (const float4*)(x + (size_t)i * 32);
#pragma unroll
    for (int q = 0; q < 8; ++q) {
        float4 v = xp[q];
        xr[4*q] = v.x; xr[4*q+1] = v.y; xr[4*q+2] = v.z; xr[4*q+3] = v.w;
    }
    float di = dinv[i];
    float o[16];
#pragma unroll
    for (int j = 0; j < 16; ++j) {
        float a = 0.f;
#pragma unroll
        for (int k = 0; k < 32; ++k) a += xr[k] * sW[k * 16 + j];
        o[j] = a * di;
    }
    float4* gp = (float4*)(g1 + (size_t)i * 16);
#pragma unroll
    for (int q = 0; q < 4; ++q)
        gp[q] = make_float4(o[4*q], o[4*q+1], o[4*q+2], o[4*q+3]);
}

// ======================= CSR build (scan) =======================

// block-local exclusive scan of hist -> rp, block totals -> partials
__global__ __launch_bounds__(BLK) void k_scan_block(const int* __restrict__ hist, int N,
                                                    int* __restrict__ rp,
                                                    int* __restrict__ partials) {
    __shared__ int sh[BLK];
    int i = blockIdx.x * BLK + threadIdx.x;
    int v = (i < N) ? hist[i] : 0;
    int sum = v;
    sh[threadIdx.x] = sum;
    __syncthreads();
    for (int off = 1; off < BLK; off <<= 1) {
        int t = (threadIdx.x >= off) ? sh[threadIdx.x - off] : 0;
        __syncthreads();
        sum += t;
        sh[threadIdx.x] = sum;
        __syncthreads();
    }
    if (i < N) rp[i] = sum - v;  // block-local exclusive
    if (threadIdx.x == BLK - 1) partials[blockIdx.x] = sum;
}

// single-block exclusive scan of partials (NB <= 512), in-place
__global__ __launch_bounds__(512) void k_scan_partials(int* __restrict__ partials, int NB) {
    __shared__ int sh[512];
    int v = (threadIdx.x < NB) ? partials[threadIdx.x] : 0;
    int sum = v;
    sh[threadIdx.x] = sum;
    __syncthreads();
    for (int off = 1; off < 512; off <<= 1) {
        int t = (threadIdx.x >= off) ? sh[threadIdx.x - off] : 0;
        __syncthreads();
        sum += t;
        sh[threadIdx.x] = sum;
        __syncthreads();
    }
    if (threadIdx.x < NB) partials[threadIdx.x] = sum - v;  // exclusive
}

// rp[i] += partials[block]; cursor[i] = rp[i]; rp[N] = total
__global__ __launch_bounds__(BLK) void k_scan_add(int* __restrict__ rp,
                                                  const int* __restrict__ partials,
                                                  const int* __restrict__ hist,
                                                  int* __restrict__ cursor, int N) {
    int i = blockIdx.x * BLK + threadIdx.x;
    if (i < N) {
        int v = rp[i] + partials[blockIdx.x];
        rp[i] = v;
        cursor[i] = v;
        if (i == N - 1) rp[N] = v + hist[i];
    }
}

// scatter edges into CSR slots: csr[pos] = src[e]
__global__ __launch_bounds__(BLK) void k_fill(const int* __restrict__ src,
                                              const int* __restrict__ dst, int E, int N,
                                              int* __restrict__ cursor,
                                              int* __restrict__ csr) {
    int i = blockIdx.x * BLK + threadIdx.x;
    if (i < E) {
        int d = dst[i];
        int s = src[i];
        if ((unsigned)d < (unsigned)N && (unsigned)s < (unsigned)N) {
            int pos = atomicAdd(&cursor[d], 1);
            csr[pos] = s;
        }
    }
}

// ======================= fused aggregation kernels =======================

// layer1 aggregate (gather over CSR) + epilogue + layer2 transform+prescale.
// one wave per node; 64 lanes = 4 edge-slots x 16 features.
__global__ __launch_bounds__(BLK) void k_agg1(const int* __restrict__ rp,
                                              const int* __restrict__ csr,
                                              const float* __restrict__ g1,
                                              const float* __restrict__ dinv,
                                              const float* __restrict__ b1,
                                              const float* __restrict__ W2,
                                              float* __restrict__ g2, int N) {
    __shared__ float sW[16 * 8];
    __shared__ float sb[16];
    if (threadIdx.x < 128) sW[threadIdx.x] = W2[threadIdx.x];
    if (threadIdx.x < 16) sb[threadIdx.x] = b1[threadIdx.x];
    __syncthreads();
    int wid = blockIdx.x * (BLK / 64) + (threadIdx.x >> 6);
    if (wid >= N) return;  // wave-uniform exit
    int lane = threadIdx.x & 63;
    int f = lane & 15;
    int slot = lane >> 4;  // 0..3
    int base = rp[wid], end = rp[wid + 1];
    float acc = 0.f;
    for (int k = base + slot; k < end; k += 4) {
        int s = csr[k];
        acc += g1[(size_t)s * 16 + f];
    }
    // reduce the 4 edge-slots: all lanes end with the full sum for feature f
    acc += __shfl_xor(acc, 16);
    acc += __shfl_xor(acc, 32);
    float di = dinv[wid];
    float self = g1[(size_t)wid * 16 + f];
    float h = fmaxf((acc + self) * di + sb[f], 0.f);  // h1[f], duplicated x4
    // 16 -> 8 dense: o = lane&7; dot over the 16 features via shfl broadcast
    int gbase = lane & ~15;
    int o = lane & 7;
    float a = 0.f;
#pragma unroll
    for (int kk = 0; kk < 16; ++kk) {
        float hv = __shfl(h, gbase + kk);
        a += hv * sW[kk * 8 + o];
    }
    if (lane < 8) g2[(size_t)wid * 8 + lane] = a * di;
}

// layer2 aggregate + epilogue + final fc (8 -> 4) + bias -> out.
// one wave per node; 64 lanes = 8 edge-slots x 8 features.
__global__ __launch_bounds__(BLK) void k_agg2(const int* __restrict__ rp,
                                              const int* __restrict__ csr,
                                              const float* __restrict__ g2,
                                              const float* __restrict__ dinv,
                                              const float* __restrict__ b2,
                                              const float* __restrict__ Wfc,
                                              const float* __restrict__ bfc,
                                              float* __restrict__ out, int N) {
    __shared__ float sW[8 * 4];
    __shared__ float sb2[8];
    __shared__ float sbf[4];
    if (threadIdx.x < 32) sW[threadIdx.x] = Wfc[threadIdx.x];
    if (threadIdx.x < 8) sb2[threadIdx.x] = b2[threadIdx.x];
    if (threadIdx.x < 4) sbf[threadIdx.x] = bfc[threadIdx.x];
    __syncthreads();
    int wid = blockIdx.x * (BLK / 64) + (threadIdx.x >> 6);
    if (wid >= N) return;
    int lane = threadIdx.x & 63;
    int f = lane & 7;
    int slot = lane >> 3;  // 0..7
    int base = rp[wid], end = rp[wid + 1];
    float acc = 0.f;
    for (int k = base + slot; k < end; k += 8) {
        int s = csr[k];
        acc += g2[(size_t)s * 8 + f];
    }
    acc += __shfl_xor(acc, 8);
    acc += __shfl_xor(acc, 16);
    acc += __shfl_xor(acc, 32);
    float di = dinv[wid];
    float self = g2[(size_t)wid * 8 + f];
    float h = fmaxf((acc + self) * di + sb2[f], 0.f);  // h2[f], duplicated x8
    int gbase = lane & ~7;
    int o = lane & 3;
    float a = 0.f;
#pragma unroll
    for (int j = 0; j < 8; ++j) {
        float hv = __shfl(h, gbase + j);
        a += hv * sW[j * 4 + o];
    }
    if (lane < 4) out[(size_t)wid * 4 + lane] = a + sbf[lane];
}

// ======================= fallback (round-1 atomic path) =======================

__global__ __launch_bounds__(BLK) void k_count(const int* __restrict__ dst, int E, int N,
                                               float* __restrict__ cnt) {
    int i = blockIdx.x * BLK + threadIdx.x;
    if (i < E) {
        int d = dst[i];
        if ((unsigned)d < (unsigned)N) atomicAdd(&cnt[d], 1.0f);
    }
}
__global__ __launch_bounds__(BLK) void k_dinv_f(float* __restrict__ cnt, int N) {
    int i = blockIdx.x * BLK + threadIdx.x;
    if (i < N) cnt[i] = rsqrtf(cnt[i] + 1.0f);
}
template <int F>
__global__ __launch_bounds__(BLK) void k_edge_agg(const int* __restrict__ src,
                                                  const int* __restrict__ dst,
                                                  int E, int N,
                                                  const float* __restrict__ g,
                                                  float* __restrict__ agg) {
    size_t t = (size_t)blockIdx.x * BLK + threadIdx.x;
    int e = (int)(t / F);
    int f = (int)(t & (F - 1));
    if (e >= E) return;
    int s = src[e], d = dst[e];
    if ((unsigned)s >= (unsigned)N || (unsigned)d >= (unsigned)N) return;
    atomicAdd(&agg[(size_t)d * F + f], g[(size_t)s * F + f]);
}
__global__ __launch_bounds__(BLK) void k_node1(const float* __restrict__ g1,
                                               const float* __restrict__ agg1,
                                               const float* __restrict__ dinv,
                                               const float* __restrict__ b1,
                                               const float* __restrict__ W2,
                                               float* __restrict__ g2, int N) {
    __shared__ float sW[16 * 8];
    __shared__ float sb[16];
    for (int t = threadIdx.x; t < 128; t += BLK) sW[t] = W2[t];
    if (threadIdx.x < 16) sb[threadIdx.x] = b1[threadIdx.x];
    __syncthreads();
    int i = blockIdx.x * BLK + threadIdx.x;
    if (i >= N) return;
    float di = dinv[i];
    const float4* gp = (const float4*)(g1 + (size_t)i * 16);
    const float4* ap = (const float4*)(agg1 + (size_t)i * 16);
    float h[16];
#pragma unroll
    for (int q = 0; q < 4; ++q) {
        float4 gv = gp[q], av = ap[q];
        h[4*q+0] = fmaxf((av.x + gv.x) * di + sb[4*q+0], 0.f);
        h[4*q+1] = fmaxf((av.y + gv.y) * di + sb[4*q+1], 0.f);
        h[4*q+2] = fmaxf((av.z + gv.z) * di + sb[4*q+2], 0.f);
        h[4*q+3] = fmaxf((av.w + gv.w) * di + sb[4*q+3], 0.f);
    }
    float o[8];
#pragma unroll
    for (int j = 0; j < 8; ++j) {
        float a = 0.f;
#pragma unroll
        for (int k = 0; k < 16; ++k) a += h[k] * sW[k * 8 + j];
        o[j] = a * di;
    }
    float4* op = (float4*)(g2 + (size_t)i * 8);
    op[0] = make_float4(o[0], o[1], o[2], o[3]);
    op[1] = make_float4(o[4], o[5], o[6], o[7]);
}
__global__ __launch_bounds__(BLK) void k_node2(const float* __restrict__ g2,
                                               const float* __restrict__ agg2,
                                               const float* __restrict__ dinv,
                                               const float* __restrict__ b2,
                                               const float* __restrict__ Wfc,
                                               const float* __restrict__ bfc,
                                               float* __restrict__ out, int N) {
    __shared__ float sW[8 * 4];
    __shared__ float sb2[8];
    __shared__ float sbf[4];
    if (threadIdx.x < 32) sW[threadIdx.x] = Wfc[threadIdx.x];
    if (threadIdx.x < 8) sb2[threadIdx.x] = b2[threadIdx.x];
    if (threadIdx.x < 4) sbf[threadIdx.x] = bfc[threadIdx.x];
    __syncthreads();
    int i = blockIdx.x * BLK + threadIdx.x;
    if (i >= N) return;
    float di = dinv[i];
    const float4* gp = (const float4*)(g2 + (size_t)i * 8);
    const float4* ap = (const float4*)(agg2 + (size_t)i * 8);
    float h[8];
#pragma unroll
    for (int q = 0; q < 2; ++q) {
        float4 gv = gp[q], av = ap[q];
        h[4*q+0] = fmaxf((av.x + gv.x) * di + sb2[4*q+0], 0.f);
        h[4*q+1] = fmaxf((av.y + gv.y) * di + sb2[4*q+1], 0.f);
        h[4*q+2] = fmaxf((av.z + gv.z) * di + sb2[4*q+2], 0.f);
        h[4*q+3] = fmaxf((av.w + gv.w) * di + sb2[4*q+3], 0.f);
    }
    float o[4];
#pragma unroll
    for (int k = 0; k < 4; ++k) {
        float a = sbf[k];
#pragma unroll
        for (int j = 0; j < 8; ++j) a += h[j] * sW[j * 4 + k];
        o[k] = a;
    }
    ((float4*)(out + (size_t)i * 4))[0] = make_float4(o[0], o[1], o[2], o[3]);
}

// ======================= launch =======================

static inline size_t align16w(size_t w) { return (w + 15) & ~(size_t)15; }  // 64B align (words)

extern "C" void kernel_launch(void* const* d_in, const int* in_sizes, int n_in,
                              void* d_out, int out_size, void* d_ws, size_t ws_size,
                              hipStream_t stream) {
    const float* x   = (const float*)d_in[0];
    const int*   ei  = (const int*)d_in[1];
    const float* W1  = (const float*)d_in[2];
    const float* b1  = (const float*)d_in[3];
    const float* W2  = (const float*)d_in[4];
    const float* b2  = (const float*)d_in[5];
    const float* Wfc = (const float*)d_in[6];
    const float* bfc = (const float*)d_in[7];

    int N = in_sizes[0] / 32;
    int E = in_sizes[1] / 2;
    const int* src = ei;
    const int* dst = ei + (size_t)E;

    int NB = (N + BLK - 1) / BLK;  // scan blocks

    // --- CSR-path workspace layout (words of 4B) ---
    size_t w_g1   = 0;                                   // 16N f
    size_t w_g2   = w_g1 + (size_t)16 * N;               // 8N  f
    size_t w_csr  = w_g2 + (size_t)8 * N;                // E   i
    size_t w_hist = w_csr + (size_t)E;                   // N   i
    size_t w_dinv = w_hist + (size_t)N;                  // N   f
    size_t w_rp   = w_dinv + (size_t)N;                  // N+1 i
    size_t w_cur  = align16w(w_rp + (size_t)N + 1);      // N   i
    size_t w_par  = w_cur + (size_t)N;                   // 512 i
    size_t need   = (w_par + 512) * 4;

    bool use_csr = (ws_size >= need) && (NB <= 512);

    if (use_csr) {
        float* ws   = (float*)d_ws;
        float* g1   = ws + w_g1;
        float* g2   = ws + w_g2;
        int*   csr  = (int*)(ws + w_csr);
        int*   hist = (int*)(ws + w_hist);
        float* dinv = ws + w_dinv;
        int*   rp   = (int*)(ws + w_rp);
        int*   cur  = (int*)(ws + w_cur);
        int*   par  = (int*)(ws + w_par);

        hipMemsetAsync(hist, 0, (size_t)N * 4, stream);

        k_hist<<<(E + BLK - 1) / BLK, BLK, 0, stream>>>(dst, E, N, hist);
        k_dinv_i<<<NB, BLK, 0, stream>>>(hist, dinv, N);
        k_scan_block<<<NB, BLK, 0, stream>>>(hist, N, rp, par);
        k_scan_partials<<<1, 512, 0, stream>>>(par, NB);
        k_scan_add<<<NB, BLK, 0, stream>>>(rp, par, hist, cur, N);
        k_fill<<<(E + BLK - 1) / BLK, BLK, 0, stream>>>(src, dst, E, N, cur, csr);
        k_transform1<<<NB, BLK, 0, stream>>>(x, W1, dinv, g1, N);

        int nodes_per_blk = BLK / 64;
        int gagg = (N + nodes_per_blk - 1) / nodes_per_blk;
        k_agg1<<<gagg, BLK, 0, stream>>>(rp, csr, g1, dinv, b1, W2, g2, N);
        k_agg2<<<gagg, BLK, 0, stream>>>(rp, csr, g2, dinv, b2, Wfc, bfc, (float*)d_out, N);
    } else {
        // round-1 atomic fallback
        float* ws   = (float*)d_ws;
        float* dinv = ws;                       // N
        float* g1   = dinv + (size_t)N;         // 16N
        float* agg1 = g1 + (size_t)16 * N;      // 16N
        float* g2   = agg1 + (size_t)16 * N;    // 8N
        float* agg2 = g2 + (size_t)8 * N;       // 8N

        hipMemsetAsync(dinv, 0, (size_t)N * 4, stream);
        hipMemsetAsync(agg1, 0, (size_t)16 * N * 4, stream);
        hipMemsetAsync(agg2, 0, (size_t)8 * N * 4, stream);

        k_count<<<(E + BLK - 1) / BLK, BLK, 0, stream>>>(dst, E, N, dinv);
        k_dinv_f<<<(N + BLK - 1) / BLK, BLK, 0, stream>>>(dinv, N);
        k_transform1<<<(N + BLK - 1) / BLK, BLK, 0, stream>>>(x, W1, dinv, g1, N);
        {
            size_t tot = (size_t)E * 16;
            k_edge_agg<16><<<(unsigned)((tot + BLK - 1) / BLK), BLK, 0, stream>>>(src, dst, E, N, g1, agg1);
        }
        k_node1<<<(N + BLK - 1) / BLK, BLK, 0, stream>>>(g1, agg1, dinv, b1, W2, g2, N);
        {
            size_t tot = (size_t)E * 8;
            k_edge_agg<8><<<(unsigned)((tot + BLK - 1) / BLK), BLK, 0, stream>>>(src, dst, E, N, g2, agg2);
        }
        k_node2<<<(N + BLK - 1) / BLK, BLK, 0, stream>>>(g2, agg2, dinv, b2, Wfc, bfc, (float*)d_out, N);
    }
}